// Round 3
// baseline (1211.442 us; speedup 1.0000x reference)
//
#include <hip/hip_runtime.h>
#include <math.h>
#include <stdint.h>

namespace {
constexpr int kN = 768, kCT = 768, kCS = 384, kCP = 128, kNH = 16, kHD = 48;
constexpr float kEps = 1e-5f;
constexpr float kQScale = 0.14433756729740643f;  // 1/sqrt(48)
}

typedef __attribute__((ext_vector_type(8))) short short8;
typedef __attribute__((ext_vector_type(4))) float floatx4;

__device__ __forceinline__ float sigf(float x) { return 1.f / (1.f + expf(-x)); }
__device__ __forceinline__ unsigned short f2bf(float x) {  // RNE bf16 round
  uint32_t v = __builtin_bit_cast(uint32_t, x);
  return (unsigned short)((v + 0x7fffu + ((v >> 16) & 1u)) >> 16);
}
__device__ __forceinline__ float bf2f(unsigned short u) {
  uint32_t v = ((uint32_t)u) << 16;
  return __builtin_bit_cast(float, v);
}

#if __has_builtin(__builtin_amdgcn_global_load_lds)
#define HAVE_GLL 1
#define ASYNC_COPY16(gp, lp)                                                     \
  __builtin_amdgcn_global_load_lds((const __attribute__((address_space(1))) void*)(gp), \
                                   (__attribute__((address_space(3))) void*)(lp), 16, 0, 0)
#else
#define HAVE_GLL 0
#endif

// ---------------- coalesced weight transpose -> bf16, 32x32 LDS tiles ---------------------
// All sources are [K][768] fp32 row-major; dst[n*K+k] = bf16(src[k*768+n]).
__global__ __launch_bounds__(256) void transpose_pack_kernel(
    const float* __restrict__ Wg, const float* __restrict__ Wb,
    const float* __restrict__ Wq, const float* __restrict__ Wk,
    const float* __restrict__ Wv, const float* __restrict__ Wgate,
    const float* __restrict__ Wog, const float* __restrict__ Wout,
    unsigned short* __restrict__ p_adaT, unsigned short* __restrict__ p_qkvT,
    unsigned short* __restrict__ WogT, unsigned short* __restrict__ WoutT) {
  __shared__ float tile[32][33];
  // tiles per matrix: K/32 * 24 ; cumulative
  const int cum[8] = {288, 576, 1152, 1728, 2304, 2880, 3168, 3744};
  const int srcK[8] = {384, 384, 768, 768, 768, 768, 384, 768};
  int bid = blockIdx.x;
  int m = 0;
#pragma unroll
  for (int q = 0; q < 8; ++q)
    if (bid >= cum[q]) m = q + 1;
  const int base = m ? cum[m - 1] : 0;
  const int tloc = bid - base;
  const float* src = m == 0 ? Wg : m == 1 ? Wb : m == 2 ? Wq : m == 3 ? Wk
                   : m == 4 ? Wv : m == 5 ? Wgate : m == 6 ? Wog : Wout;
  unsigned short* dst =
      m == 0 ? p_adaT : m == 1 ? (p_adaT + 768 * 384)
    : m == 2 ? p_qkvT : m == 3 ? (p_qkvT + 768 * 768)
    : m == 4 ? (p_qkvT + 2 * 768 * 768) : m == 5 ? (p_qkvT + 3 * 768 * 768)
    : m == 6 ? WogT : WoutT;
  const int K = srcK[m];
  const int bk = tloc / 24, bn = tloc % 24;
  const int k0 = bk * 32, n0 = bn * 32;
  const int tx = threadIdx.x & 31, ty = threadIdx.x >> 5;
#pragma unroll
  for (int r = 0; r < 4; ++r)
    tile[ty + 8 * r][tx] = src[(size_t)(k0 + ty + 8 * r) * 768 + n0 + tx];
  __syncthreads();
#pragma unroll
  for (int r = 0; r < 4; ++r)
    dst[(size_t)(n0 + ty + 8 * r) * K + k0 + tx] = f2bf(tile[tx][ty + 8 * r]);
}

// ---------------- pack (small): fused biases, s->bf16, pairbias precompute ----------------
__global__ __launch_bounds__(256) void pack_kernel(
    const float* __restrict__ bg, const float* __restrict__ bq,
    const float* __restrict__ s, const float* __restrict__ Wpb,
    const float* __restrict__ gamma, const float* __restrict__ beta,
    float* __restrict__ pb_ada, float* __restrict__ pb_qk,
    unsigned short* __restrict__ s_bf, unsigned short* __restrict__ gamWT,
    float* __restrict__ pairC) {
  const int T1 = 1536;
  const int T2 = T1 + 3072;
  const int T3 = T2 + 1536 * 384;
  const int T4 = T3 + 2048;
  const int T5 = T4 + 32;
  int idx = blockIdx.x * 256 + threadIdx.x;
  if (idx < T1) {
    pb_ada[idx] = (idx < 768) ? bg[idx] : 0.f;
  } else if (idx < T2) {
    int c = idx - T1;
    pb_qk[c] = (c < 768) ? bq[c] : 0.f;
  } else if (idx < T3) {
    int r = idx - T2;
    s_bf[r] = f2bf(s[r]);
  } else if (idx < T4) {  // gamWT[h][c] = bf16(gamma[c]*Wpb[c][h])  (MFMA A-operand layout)
    int r = idx - T3;
    int h = r >> 7, c = r & 127;
    gamWT[r] = f2bf(gamma[c] * Wpb[c * 16 + h]);
  } else if (idx < T5) {  // pairC[0:16]=sum_c beta*Wpb, pairC[16:32]=sum_c gamma*Wpb
    int r = idx - T4;
    float acc = 0.f;
    if (r < 16) {
      for (int c = 0; c < 128; ++c) acc += beta[c] * Wpb[c * 16 + r];
      pairC[r] = acc;
    } else {
      int h = r - 16;
      for (int c = 0; c < 128; ++c) acc += gamma[c] * Wpb[c * 16 + h];
      pairC[r] = acc;
    }
  }
}

// ---------------- LayerNorm over last dim (no affine), templated C, fp32 out --------------
template <int C>
__global__ __launch_bounds__(256) void ln_kernel(const float* __restrict__ x,
                                                 float* __restrict__ y) {
  constexpr int NV = (C + 255) / 256;
  const int row = blockIdx.x;
  const float* xr = x + (size_t)row * C;
  float vals[NV];
  float s = 0.f, ss = 0.f;
#pragma unroll
  for (int it = 0; it < NV; ++it) {
    int c = threadIdx.x + it * 256;
    float v = (c < C) ? xr[c] : 0.f;
    vals[it] = v;
    s += v;
    ss = fmaf(v, v, ss);
  }
#pragma unroll
  for (int m = 1; m < 64; m <<= 1) { s += __shfl_xor(s, m); ss += __shfl_xor(ss, m); }
  __shared__ float red[8];
  __shared__ float mb[2];
  const int wid = threadIdx.x >> 6, lane = threadIdx.x & 63;
  if (lane == 0) { red[wid * 2] = s; red[wid * 2 + 1] = ss; }
  __syncthreads();
  if (threadIdx.x == 0) {
    float S = red[0] + red[2] + red[4] + red[6];
    float SS = red[1] + red[3] + red[5] + red[7];
    float mean = S / C;
    float var = SS / C - mean * mean;
    mb[0] = mean;
    mb[1] = rsqrtf(var + kEps);
  }
  __syncthreads();
  const float mean = mb[0], rs = mb[1];
#pragma unroll
  for (int it = 0; it < NV; ++it) {
    int c = threadIdx.x + it * 256;
    if (c < C) y[(size_t)row * C + c] = (vals[it] - mean) * rs;
  }
}

// ---------------- LayerNorm, templated C, bf16 out ---------------------------------------
template <int C>
__global__ __launch_bounds__(256) void ln_bf_kernel(const float* __restrict__ x,
                                                    unsigned short* __restrict__ y) {
  constexpr int NV = (C + 255) / 256;
  const int row = blockIdx.x;
  const float* xr = x + (size_t)row * C;
  float vals[NV];
  float s = 0.f, ss = 0.f;
#pragma unroll
  for (int it = 0; it < NV; ++it) {
    int c = threadIdx.x + it * 256;
    float v = (c < C) ? xr[c] : 0.f;
    vals[it] = v;
    s += v;
    ss = fmaf(v, v, ss);
  }
#pragma unroll
  for (int m = 1; m < 64; m <<= 1) { s += __shfl_xor(s, m); ss += __shfl_xor(ss, m); }
  __shared__ float red[8];
  __shared__ float mb[2];
  const int wid = threadIdx.x >> 6, lane = threadIdx.x & 63;
  if (lane == 0) { red[wid * 2] = s; red[wid * 2 + 1] = ss; }
  __syncthreads();
  if (threadIdx.x == 0) {
    float S = red[0] + red[2] + red[4] + red[6];
    float SS = red[1] + red[3] + red[5] + red[7];
    float mean = S / C;
    float var = SS / C - mean * mean;
    mb[0] = mean;
    mb[1] = rsqrtf(var + kEps);
  }
  __syncthreads();
  const float mean = mb[0], rs = mb[1];
#pragma unroll
  for (int it = 0; it < NV; ++it) {
    int c = threadIdx.x + it * 256;
    if (c < C) y[(size_t)row * C + c] = f2bf((vals[it] - mean) * rs);
  }
}

// ---------------- a_norm = sigmoid(G)*a_ln + Bv  -> bf16 ---------------------------------
__global__ __launch_bounds__(256) void anorm_kernel(const float* __restrict__ gb,
                                                    const float* __restrict__ a_ln,
                                                    unsigned short* __restrict__ a_norm) {
  int idx = blockIdx.x * 256 + threadIdx.x;  // < 1536*768
  int row = idx / kCT, col = idx % kCT;
  float g = gb[(size_t)row * (2 * kCT) + col];
  float bv = gb[(size_t)row * (2 * kCT) + kCT + col];
  a_norm[idx] = f2bf(sigf(g) * a_ln[idx] + bv);
}

// ---------------- bf16 MFMA GEMM: C[M,N] = A[M,K] @ Wt[N,K]^T, fp32 out -------------------
// BMx128 tile (BM=128 or 64), BK=32, 4 waves, 16x16x32 MFMA, XOR-swizzled LDS,
// global_load_lds width 16. Epilogue: +bias[col], sigmoid col>=sig_start, *aux[row,col].
template <int BM>
__global__ __launch_bounds__(256) void gemm_bf_kernel(
    const unsigned short* __restrict__ A, const unsigned short* __restrict__ Wt,
    const float* __restrict__ bias, const float* __restrict__ aux,
    float* __restrict__ C, int M, int Nn, int K, int sig_start) {
  constexpr int TM = BM / 32;  // 4 (BM=128) or 2 (BM=64)
  __shared__ __align__(16) unsigned short As[BM * 32];
  __shared__ __align__(16) unsigned short Bs[128 * 32];
  const int t = threadIdx.x;
  const int wid = t >> 6, lane = t & 63;
  const int quad = lane >> 4, m16 = lane & 15;
  const int wm = (wid >> 1) * (BM / 2), wn = (wid & 1) * 64;
  const int bm = blockIdx.y * BM, bn = blockIdx.x * 128;
  const int swz = quad ^ ((m16 >> 1) & 3);
  // staging: chunk ci holds (row=ci>>2, kchunk=(ci&3)^((row>>1)&3)) of this k0-slab
  const int ci0 = t, ci1 = t + 256;
  const int am0 = ci0 >> 2, ak0 = ((ci0 & 3) ^ ((am0 >> 1) & 3)) * 8;
  const int am1 = ci1 >> 2, ak1 = ((ci1 & 3) ^ ((am1 >> 1) & 3)) * 8;
  const unsigned short* ga0 = A + (size_t)(bm + am0) * K + ak0;
  const unsigned short* ga1 = A + (size_t)(bm + am1) * K + ak1;  // BM==128 only
  const unsigned short* gw0 = Wt + (size_t)(bn + am0) * K + ak0;
  const unsigned short* gw1 = Wt + (size_t)(bn + am1) * K + ak1;
  floatx4 acc[TM][4] = {};
  for (int k0 = 0; k0 < K; k0 += 32) {
    __syncthreads();
#if HAVE_GLL
    ASYNC_COPY16(ga0 + k0, &As[ci0 * 8]);
    if constexpr (BM == 128) ASYNC_COPY16(ga1 + k0, &As[ci1 * 8]);
    ASYNC_COPY16(gw0 + k0, &Bs[ci0 * 8]);
    ASYNC_COPY16(gw1 + k0, &Bs[ci1 * 8]);
#else
    short8 ra0 = *(const short8*)(ga0 + k0);
    short8 rw0 = *(const short8*)(gw0 + k0);
    short8 rw1 = *(const short8*)(gw1 + k0);
    *(short8*)&As[ci0 * 8] = ra0;
    if constexpr (BM == 128) {
      short8 ra1 = *(const short8*)(ga1 + k0);
      *(short8*)&As[ci1 * 8] = ra1;
    }
    *(short8*)&Bs[ci0 * 8] = rw0;
    *(short8*)&Bs[ci1 * 8] = rw1;
#endif
    __syncthreads();
    short8 af[TM], bfv[4];
#pragma unroll
    for (int tm = 0; tm < TM; ++tm)
      af[tm] = *(const short8*)&As[(wm + tm * 16 + m16) * 32 + swz * 8];
#pragma unroll
    for (int tn = 0; tn < 4; ++tn)
      bfv[tn] = *(const short8*)&Bs[(wn + tn * 16 + m16) * 32 + swz * 8];
#pragma unroll
    for (int tm = 0; tm < TM; ++tm)
#pragma unroll
      for (int tn = 0; tn < 4; ++tn)
        acc[tm][tn] = __builtin_amdgcn_mfma_f32_16x16x32_bf16(af[tm], bfv[tn], acc[tm][tn], 0, 0, 0);
  }
  // epilogue: C/D layout col=lane&15, row=quad*4+reg
#pragma unroll
  for (int tm = 0; tm < TM; ++tm) {
    const int row0 = bm + wm + tm * 16 + quad * 4;
#pragma unroll
    for (int tn = 0; tn < 4; ++tn) {
      const int col = bn + wn + tn * 16 + m16;
      const float badd = bias ? bias[col] : 0.f;
#pragma unroll
      for (int r = 0; r < 4; ++r) {
        float v = acc[tm][tn][r] + badd;
        if (col >= sig_start) v = sigf(v);
        if (aux) v *= aux[(size_t)(row0 + r) * Nn + col];
        C[(size_t)(row0 + r) * Nn + col] = v;
      }
    }
  }
}

// ---------------- pair bias v4: MFMA over h, LN folded, z staged bf16 in LDS --------------
// Per block: (b, i, 128-j tile). Phase 1: stream z (fp32), per-j stats in fp32, stage
// bf16 z tile in LDS [128j][136 shorts] (odd 16B stride -> conflict-free). Phase 2:
// 4 waves x 8 MFMA 16x16x32 (A=gamWT[16h][128c] in regs, B=z tile). D: col=j, row=h.
// pb[b,h,i,j] = rs*(dot - mean*gwsum[h]) + constB[h] + mask[b,i,j]
__global__ __launch_bounds__(256, 4) void pairbias3_kernel(
    const float* __restrict__ z, const float* __restrict__ mask,
    const unsigned short* __restrict__ gamWT, const float* __restrict__ pairC,
    unsigned short* __restrict__ pb) {
  __shared__ __align__(16) unsigned short zbf[128 * 136];
  __shared__ float2 pstat[256];
  __shared__ float2 mstat[128];
  const int t = threadIdx.x;
  const int jj = t & 127, half = t >> 7;
  const int b = blockIdx.z, i = blockIdx.y;
  const int j0 = blockIdx.x * 128;
  const float* zrow = &z[((size_t)(b * kN + i) * kN + j0 + jj) * kCP + half * 64];
  float sum = 0.f, ss = 0.f;
#pragma unroll
  for (int g = 0; g < 2; ++g) {  // two groups of 32 channels
    float4 v[8];
#pragma unroll
    for (int u = 0; u < 8; ++u) v[u] = ((const float4*)zrow)[g * 8 + u];
#pragma unroll
    for (int u = 0; u < 8; ++u) {
      sum += (v[u].x + v[u].y) + (v[u].z + v[u].w);
      ss = fmaf(v[u].x, v[u].x, ss);
      ss = fmaf(v[u].y, v[u].y, ss);
      ss = fmaf(v[u].z, v[u].z, ss);
      ss = fmaf(v[u].w, v[u].w, ss);
    }
#pragma unroll
    for (int k = 0; k < 4; ++k) {  // 8 channels -> one 16B LDS chunk
      short8 pk;
      const float4 a = v[2 * k], bb = v[2 * k + 1];
      pk[0] = (short)f2bf(a.x); pk[1] = (short)f2bf(a.y);
      pk[2] = (short)f2bf(a.z); pk[3] = (short)f2bf(a.w);
      pk[4] = (short)f2bf(bb.x); pk[5] = (short)f2bf(bb.y);
      pk[6] = (short)f2bf(bb.z); pk[7] = (short)f2bf(bb.w);
      const int c16 = half * 8 + g * 4 + k;
      *(short8*)&zbf[(jj * 17 + c16) * 8] = pk;
    }
  }
  pstat[t] = make_float2(sum, ss);
  __syncthreads();
  if (t < 128) {
    const float S = pstat[t].x + pstat[t + 128].x;
    const float SS = pstat[t].y + pstat[t + 128].y;
    const float mean = S * (1.f / 128.f);
    const float var = SS * (1.f / 128.f) - mean * mean;
    mstat[t] = make_float2(mean, rsqrtf(var + kEps));
  }
  __syncthreads();
  const int wid = t >> 6, lane = t & 63;
  const int m16 = lane & 15, quad = lane >> 4;
  short8 ga[4];
#pragma unroll
  for (int kk = 0; kk < 4; ++kk)
    ga[kk] = *(const short8*)&gamWT[m16 * 128 + kk * 32 + quad * 8];
  const float4 cb = ((const float4*)pairC)[quad];      // constB[h], h=quad*4+r
  const float4 gs = ((const float4*)pairC)[4 + quad];  // gwsum[h]
#pragma unroll
  for (int u = 0; u < 2; ++u) {
    const int tt = wid * 2 + u;
    const int jloc = tt * 16 + m16;
    floatx4 acc = {};
#pragma unroll
    for (int kk = 0; kk < 4; ++kk) {
      const short8 bf = *(const short8*)&zbf[(jloc * 17 + kk * 4 + quad) * 8];
      acc = __builtin_amdgcn_mfma_f32_16x16x32_bf16(ga[kk], bf, acc, 0, 0, 0);
    }
    const float mean = mstat[jloc].x, rs = mstat[jloc].y;
    const float mk = mask[(size_t)(b * kN + i) * kN + j0 + jloc];
    const size_t obase = ((size_t)(b * kNH + quad * 4) * kN + i) * kN + j0 + jloc;
#pragma unroll
    for (int r = 0; r < 4; ++r) {
      const float gsr = r == 0 ? gs.x : r == 1 ? gs.y : r == 2 ? gs.z : gs.w;
      const float cbr = r == 0 ? cb.x : r == 1 ? cb.y : r == 2 ? cb.z : cb.w;
      const float res = fmaf(rs, fmaf(-mean, gsr, acc[r]), cbr) + mk;
      pb[obase + (size_t)r * kN * kN] = f2bf(res);
    }
  }
}

// ---------------- attention: per-wave (b,h,i); 16 waves/block share k/v LDS tiles ---------
// k/v staged once per 16 query rows with register prefetch of the next chunk overlapping
// the current chunk's compute.
__global__ __launch_bounds__(1024) void attn_kernel(
    const float* __restrict__ qkvg, const unsigned short* __restrict__ pb,
    unsigned short* __restrict__ o_out) {
  __shared__ float kt[64 * 52];
  __shared__ float vt[64 * 52];
  __shared__ float qs[16][48];
  const int b = blockIdx.z, h = blockIdx.y;
  const int t = threadIdx.x, wid = t >> 6, lane = t & 63;
  const int i = blockIdx.x * 16 + wid;
  const size_t rowi = (size_t)(b * kN + i) * (4 * kCT);
  if (lane < 12) {
    float4 q4 = *(const float4*)&qkvg[rowi + h * kHD + lane * 4];
    qs[wid][lane * 4 + 0] = q4.x * kQScale;
    qs[wid][lane * 4 + 1] = q4.y * kQScale;
    qs[wid][lane * 4 + 2] = q4.z * kQScale;
    qs[wid][lane * 4 + 3] = q4.w * kQScale;
  }
  // loader role: threads [0,768) each own one (jl,d4) float4 of k and of v per chunk
  const int jl = t / 12, d4 = t % 12;
  const bool loader = (t < 768);
  float4 kreg, vreg;
  if (loader) {
    const size_t rowj = (size_t)(b * kN + jl) * (4 * kCT);
    kreg = *(const float4*)&qkvg[rowj + kCT + h * kHD + d4 * 4];
    vreg = *(const float4*)&qkvg[rowj + 2 * kCT + h * kHD + d4 * 4];
  }
  float o[48];
#pragma unroll
  for (int d = 0; d < 48; ++d) o[d] = 0.f;
  float mrun = -INFINITY, lsum = 0.f;
  const unsigned short* pbrow = &pb[((size_t)(b * kNH + h) * kN + i) * kN];
  for (int c = 0; c < 12; ++c) {
    __syncthreads();  // previous chunk's consumers done
    if (loader) {
      *(float4*)&kt[jl * 52 + d4 * 4] = kreg;
      *(float4*)&vt[jl * 52 + d4 * 4] = vreg;
    }
    __syncthreads();
    if (loader && c < 11) {  // prefetch next chunk; latency hides under compute below
      const size_t rowj = (size_t)(b * kN + (c + 1) * 64 + jl) * (4 * kCT);
      kreg = *(const float4*)&qkvg[rowj + kCT + h * kHD + d4 * 4];
      vreg = *(const float4*)&qkvg[rowj + 2 * kCT + h * kHD + d4 * 4];
    }
    // logit with 4 independent accumulator chains
    float l0 = bf2f(pbrow[c * 64 + lane]), l1 = 0.f, l2 = 0.f, l3 = 0.f;
#pragma unroll
    for (int d4i = 0; d4i < 12; ++d4i) {
      float4 kk = *(const float4*)&kt[lane * 52 + d4i * 4];
      float4 qq = *(const float4*)&qs[wid][d4i * 4];
      l0 = fmaf(qq.x, kk.x, l0);
      l1 = fmaf(qq.y, kk.y, l1);
      l2 = fmaf(qq.z, kk.z, l2);
      l3 = fmaf(qq.w, kk.w, l3);
    }
    float logit = (l0 + l1) + (l2 + l3);
    float mx = logit;
#pragma unroll
    for (int m = 1; m < 64; m <<= 1) mx = fmaxf(mx, __shfl_xor(mx, m));
    const float mnew = fmaxf(mrun, mx);
    const float alpha = expf(mrun - mnew);
    const float p = expf(logit - mnew);
    lsum = fmaf(lsum, alpha, p);
#pragma unroll
    for (int d4i = 0; d4i < 12; ++d4i) {
      float4 vv = *(const float4*)&vt[lane * 52 + d4i * 4];
      o[d4i * 4 + 0] = fmaf(o[d4i * 4 + 0], alpha, p * vv.x);
      o[d4i * 4 + 1] = fmaf(o[d4i * 4 + 1], alpha, p * vv.y);
      o[d4i * 4 + 2] = fmaf(o[d4i * 4 + 2], alpha, p * vv.z);
      o[d4i * 4 + 3] = fmaf(o[d4i * 4 + 3], alpha, p * vv.w);
    }
    mrun = mnew;
  }
#pragma unroll
  for (int m = 1; m < 64; m <<= 1) lsum += __shfl_xor(lsum, m);
#pragma unroll
  for (int d = 0; d < 48; ++d) {
#pragma unroll
    for (int m = 1; m < 64; m <<= 1) o[d] += __shfl_xor(o[d], m);
  }
  if (lane == 0) {
    const float inv = 1.f / lsum;
    unsigned short* orow = o_out + (size_t)(b * kN + i) * kCT + h * kHD;
#pragma unroll
    for (int d4i = 0; d4i < 12; ++d4i) {
      float4 g4 = *(const float4*)&qkvg[rowi + 3 * kCT + h * kHD + d4i * 4];
      uint32_t u0 = (uint32_t)f2bf(g4.x * o[d4i * 4 + 0] * inv) |
                    ((uint32_t)f2bf(g4.y * o[d4i * 4 + 1] * inv) << 16);
      uint32_t u1 = (uint32_t)f2bf(g4.z * o[d4i * 4 + 2] * inv) |
                    ((uint32_t)f2bf(g4.w * o[d4i * 4 + 3] * inv) << 16);
      *(uint32_t*)&orow[d4i * 4 + 0] = u0;
      *(uint32_t*)&orow[d4i * 4 + 2] = u1;
    }
  }
}

// ==========================================================================================
extern "C" void kernel_launch(void* const* d_in, const int* in_sizes, int n_in,
                              void* d_out, int out_size, void* d_ws, size_t ws_size,
                              hipStream_t stream) {
  const float* a      = (const float*)d_in[0];
  const float* s      = (const float*)d_in[1];
  const float* z      = (const float*)d_in[2];
  const float* mask   = (const float*)d_in[3];
  const float* Wg_ada = (const float*)d_in[4];
  const float* bg_ada = (const float*)d_in[5];
  const float* Wb_ada = (const float*)d_in[6];
  const float* Wq     = (const float*)d_in[7];
  const float* bq     = (const float*)d_in[8];
  const float* Wk     = (const float*)d_in[9];
  const float* Wv     = (const float*)d_in[10];
  const float* Wpb    = (const float*)d_in[11];
  const float* pn_g   = (const float*)d_in[12];
  const float* pn_b   = (const float*)d_in[13];
  const float* Wgate  = (const float*)d_in[14];
  const float* Wout   = (const float*)d_in[15];
  const float* Wog    = (const float*)d_in[16];
  const float* bog    = (const float*)d_in[17];
  float* out = (float*)d_out;

  char* p = (char*)d_ws;
  auto alloc = [&](size_t bytes) -> char* {
    char* r = p;
    p += (bytes + 255) & ~(size_t)255;
    return r;
  };
  float* a_ln  = (float*)alloc((size_t)1536 * 768 * 4);
  float* gb    = (float*)alloc((size_t)1536 * 1536 * 4);
  float* qkvg  = (float*)alloc((size_t)1536 * 3072 * 4);
  float* ogate = (float*)alloc((size_t)1536 * 768 * 4);
  unsigned short* s_ln   = (unsigned short*)alloc((size_t)1536 * 384 * 2);
  unsigned short* a_nrm  = (unsigned short*)alloc((size_t)1536 * 768 * 2);
  unsigned short* s_bf   = (unsigned short*)alloc((size_t)1536 * 384 * 2);
  unsigned short* o_g    = (unsigned short*)alloc((size_t)1536 * 768 * 2);
  unsigned short* pbias  = (unsigned short*)alloc((size_t)2 * 16 * 768 * 768 * 2);
  unsigned short* p_adaT = (unsigned short*)alloc((size_t)1536 * 384 * 2);
  unsigned short* p_qkvT = (unsigned short*)alloc((size_t)3072 * 768 * 2);
  unsigned short* WogT   = (unsigned short*)alloc((size_t)768 * 384 * 2);
  unsigned short* WoutT  = (unsigned short*)alloc((size_t)768 * 768 * 2);
  unsigned short* gamWT  = (unsigned short*)alloc(2048 * 2);
  float* pb_ada = (float*)alloc(1536 * 4);
  float* pb_qk  = (float*)alloc(3072 * 4);
  float* pairC  = (float*)alloc(32 * 4);

  transpose_pack_kernel<<<dim3(3744), 256, 0, stream>>>(
      Wg_ada, Wb_ada, Wq, Wk, Wv, Wgate, Wog, Wout, p_adaT, p_qkvT, WogT, WoutT);
  const int packTot = 1536 + 3072 + 1536 * 384 + 2048 + 32;
  pack_kernel<<<dim3((packTot + 255) / 256), 256, 0, stream>>>(
      bg_ada, bq, s, Wpb, pn_g, pn_b, pb_ada, pb_qk, s_bf, gamWT, pairC);
  ln_kernel<768><<<dim3(1536), 256, 0, stream>>>(a, a_ln);
  ln_bf_kernel<384><<<dim3(1536), 256, 0, stream>>>(s, s_ln);
  // gb = [ s_ln@Wg_ada + bg | s_ln@Wb_ada ]
  gemm_bf_kernel<64><<<dim3(12, 24), 256, 0, stream>>>(
      s_ln, p_adaT, pb_ada, nullptr, gb, 1536, 1536, 384, 1 << 30);
  anorm_kernel<<<dim3(1536 * 768 / 256), 256, 0, stream>>>(gb, a_ln, a_nrm);
  // qkvg = a_norm @ [Wq|Wk|Wv|Wgate] (+bq on q, sigmoid on gate cols)
  gemm_bf_kernel<128><<<dim3(24, 12), 256, 0, stream>>>(
      a_nrm, p_qkvT, pb_qk, nullptr, qkvg, 1536, 3072, 768, 2304);
  // ogate = sigmoid(s @ Wog + bog)
  gemm_bf_kernel<64><<<dim3(6, 24), 256, 0, stream>>>(
      s_bf, WogT, bog, nullptr, ogate, 1536, 768, 384, 0);
  pairbias3_kernel<<<dim3(6, 768, 2), 256, 0, stream>>>(z, mask, gamWT, pairC, pbias);
  attn_kernel<<<dim3(48, 16, 2), 1024, 0, stream>>>(qkvg, pbias, o_g);
  // out = ogate * (o_g @ Wout)
  gemm_bf_kernel<64><<<dim3(6, 24), 256, 0, stream>>>(
      o_g, WoutT, nullptr, ogate, out, 1536, 768, 768, 1 << 30);
}

// Round 5
// 979.334 us; speedup vs baseline: 1.2370x; 1.2370x over previous
//
#include <hip/hip_runtime.h>
#include <math.h>
#include <stdint.h>

namespace {
constexpr int kN = 768, kCT = 768, kCS = 384, kCP = 128, kNH = 16, kHD = 48;
constexpr float kEps = 1e-5f;
constexpr float kQScale = 0.14433756729740643f;  // 1/sqrt(48)
}

typedef __attribute__((ext_vector_type(8))) short short8;
typedef __attribute__((ext_vector_type(4))) float floatx4;
typedef __attribute__((ext_vector_type(4))) int intx4;

__device__ __forceinline__ float sigf(float x) { return 1.f / (1.f + expf(-x)); }
__device__ __forceinline__ unsigned short f2bf(float x) {  // RNE bf16 round
  uint32_t v = __builtin_bit_cast(uint32_t, x);
  return (unsigned short)((v + 0x7fffu + ((v >> 16) & 1u)) >> 16);
}
__device__ __forceinline__ float bf2f(unsigned short u) {
  uint32_t v = ((uint32_t)u) << 16;
  return __builtin_bit_cast(float, v);
}
__device__ __forceinline__ uint32_t cvtpk(float lo, float hi) {
  uint32_t r;
  asm("v_cvt_pk_bf16_f32 %0, %1, %2" : "=v"(r) : "v"(lo), "v"(hi));
  return r;
}

#if __has_builtin(__builtin_amdgcn_global_load_lds)
#define HAVE_GLL 1
#define ASYNC_COPY16(gp, lp)                                                     \
  __builtin_amdgcn_global_load_lds((const __attribute__((address_space(1))) void*)(gp), \
                                   (__attribute__((address_space(3))) void*)(lp), 16, 0, 0)
#else
#define HAVE_GLL 0
#endif

// ---------------- coalesced weight transpose -> bf16, 32x32 LDS tiles ---------------------
__global__ __launch_bounds__(256) void transpose_pack_kernel(
    const float* __restrict__ Wg, const float* __restrict__ Wb,
    const float* __restrict__ Wq, const float* __restrict__ Wk,
    const float* __restrict__ Wv, const float* __restrict__ Wgate,
    const float* __restrict__ Wog, const float* __restrict__ Wout,
    unsigned short* __restrict__ p_adaT, unsigned short* __restrict__ p_qkvT,
    unsigned short* __restrict__ WogT, unsigned short* __restrict__ WoutT) {
  __shared__ float tile[32][33];
  const int cum[8] = {288, 576, 1152, 1728, 2304, 2880, 3168, 3744};
  const int srcK[8] = {384, 384, 768, 768, 768, 768, 384, 768};
  int bid = blockIdx.x;
  int m = 0;
#pragma unroll
  for (int q = 0; q < 8; ++q)
    if (bid >= cum[q]) m = q + 1;
  const int base = m ? cum[m - 1] : 0;
  const int tloc = bid - base;
  const float* src = m == 0 ? Wg : m == 1 ? Wb : m == 2 ? Wq : m == 3 ? Wk
                   : m == 4 ? Wv : m == 5 ? Wgate : m == 6 ? Wog : Wout;
  unsigned short* dst =
      m == 0 ? p_adaT : m == 1 ? (p_adaT + 768 * 384)
    : m == 2 ? p_qkvT : m == 3 ? (p_qkvT + 768 * 768)
    : m == 4 ? (p_qkvT + 2 * 768 * 768) : m == 5 ? (p_qkvT + 3 * 768 * 768)
    : m == 6 ? WogT : WoutT;
  const int K = srcK[m];
  const int bk = tloc / 24, bn = tloc % 24;
  const int k0 = bk * 32, n0 = bn * 32;
  const int tx = threadIdx.x & 31, ty = threadIdx.x >> 5;
#pragma unroll
  for (int r = 0; r < 4; ++r)
    tile[ty + 8 * r][tx] = src[(size_t)(k0 + ty + 8 * r) * 768 + n0 + tx];
  __syncthreads();
#pragma unroll
  for (int r = 0; r < 4; ++r)
    dst[(size_t)(n0 + ty + 8 * r) * K + k0 + tx] = f2bf(tile[tx][ty + 8 * r]);
}

// ---------------- pack (small): fused biases, s->bf16, pairbias precompute ----------------
__global__ __launch_bounds__(256) void pack_kernel(
    const float* __restrict__ bg, const float* __restrict__ bq,
    const float* __restrict__ s, const float* __restrict__ Wpb,
    const float* __restrict__ gamma, const float* __restrict__ beta,
    float* __restrict__ pb_ada, float* __restrict__ pb_qk,
    unsigned short* __restrict__ s_bf, unsigned short* __restrict__ gamWT,
    float* __restrict__ pairC) {
  const int T1 = 1536;
  const int T2 = T1 + 3072;
  const int T3 = T2 + 1536 * 384;
  const int T4 = T3 + 2048;
  const int T5 = T4 + 32;
  int idx = blockIdx.x * 256 + threadIdx.x;
  if (idx < T1) {
    pb_ada[idx] = (idx < 768) ? bg[idx] : 0.f;
  } else if (idx < T2) {
    int c = idx - T1;
    pb_qk[c] = (c < 768) ? bq[c] : 0.f;
  } else if (idx < T3) {
    int r = idx - T2;
    s_bf[r] = f2bf(s[r]);
  } else if (idx < T4) {  // gamWT[h][c] = bf16(gamma[c]*Wpb[c][h])
    int r = idx - T3;
    int h = r >> 7, c = r & 127;
    gamWT[r] = f2bf(gamma[c] * Wpb[c * 16 + h]);
  } else if (idx < T5) {
    int r = idx - T4;
    float acc = 0.f;
    if (r < 16) {
      for (int c = 0; c < 128; ++c) acc += beta[c] * Wpb[c * 16 + r];
      pairC[r] = acc;
    } else {
      int h = r - 16;
      for (int c = 0; c < 128; ++c) acc += gamma[c] * Wpb[c * 16 + h];
      pairC[r] = acc;
    }
  }
}

// ---------------- LayerNorm over last dim (no affine), templated C, fp32 out --------------
template <int C>
__global__ __launch_bounds__(256) void ln_kernel(const float* __restrict__ x,
                                                 float* __restrict__ y) {
  constexpr int NV = (C + 255) / 256;
  const int row = blockIdx.x;
  const float* xr = x + (size_t)row * C;
  float vals[NV];
  float s = 0.f, ss = 0.f;
#pragma unroll
  for (int it = 0; it < NV; ++it) {
    int c = threadIdx.x + it * 256;
    float v = (c < C) ? xr[c] : 0.f;
    vals[it] = v;
    s += v;
    ss = fmaf(v, v, ss);
  }
#pragma unroll
  for (int m = 1; m < 64; m <<= 1) { s += __shfl_xor(s, m); ss += __shfl_xor(ss, m); }
  __shared__ float red[8];
  __shared__ float mb[2];
  const int wid = threadIdx.x >> 6, lane = threadIdx.x & 63;
  if (lane == 0) { red[wid * 2] = s; red[wid * 2 + 1] = ss; }
  __syncthreads();
  if (threadIdx.x == 0) {
    float S = red[0] + red[2] + red[4] + red[6];
    float SS = red[1] + red[3] + red[5] + red[7];
    float mean = S / C;
    float var = SS / C - mean * mean;
    mb[0] = mean;
    mb[1] = rsqrtf(var + kEps);
  }
  __syncthreads();
  const float mean = mb[0], rs = mb[1];
#pragma unroll
  for (int it = 0; it < NV; ++it) {
    int c = threadIdx.x + it * 256;
    if (c < C) y[(size_t)row * C + c] = (vals[it] - mean) * rs;
  }
}

// ---------------- LayerNorm, templated C, bf16 out ---------------------------------------
template <int C>
__global__ __launch_bounds__(256) void ln_bf_kernel(const float* __restrict__ x,
                                                    unsigned short* __restrict__ y) {
  constexpr int NV = (C + 255) / 256;
  const int row = blockIdx.x;
  const float* xr = x + (size_t)row * C;
  float vals[NV];
  float s = 0.f, ss = 0.f;
#pragma unroll
  for (int it = 0; it < NV; ++it) {
    int c = threadIdx.x + it * 256;
    float v = (c < C) ? xr[c] : 0.f;
    vals[it] = v;
    s += v;
    ss = fmaf(v, v, ss);
  }
#pragma unroll
  for (int m = 1; m < 64; m <<= 1) { s += __shfl_xor(s, m); ss += __shfl_xor(ss, m); }
  __shared__ float red[8];
  __shared__ float mb[2];
  const int wid = threadIdx.x >> 6, lane = threadIdx.x & 63;
  if (lane == 0) { red[wid * 2] = s; red[wid * 2 + 1] = ss; }
  __syncthreads();
  if (threadIdx.x == 0) {
    float S = red[0] + red[2] + red[4] + red[6];
    float SS = red[1] + red[3] + red[5] + red[7];
    float mean = S / C;
    float var = SS / C - mean * mean;
    mb[0] = mean;
    mb[1] = rsqrtf(var + kEps);
  }
  __syncthreads();
  const float mean = mb[0], rs = mb[1];
#pragma unroll
  for (int it = 0; it < NV; ++it) {
    int c = threadIdx.x + it * 256;
    if (c < C) y[(size_t)row * C + c] = f2bf((vals[it] - mean) * rs);
  }
}

// ---------------- a_norm = sigmoid(G)*a_ln + Bv  -> bf16 ---------------------------------
__global__ __launch_bounds__(256) void anorm_kernel(const float* __restrict__ gb,
                                                    const float* __restrict__ a_ln,
                                                    unsigned short* __restrict__ a_norm) {
  int idx = blockIdx.x * 256 + threadIdx.x;  // < 1536*768
  int row = idx / kCT, col = idx % kCT;
  float g = gb[(size_t)row * (2 * kCT) + col];
  float bv = gb[(size_t)row * (2 * kCT) + kCT + col];
  a_norm[idx] = f2bf(sigf(g) * a_ln[idx] + bv);
}

// ---------------- bf16 MFMA GEMM: C[M,N] = A[M,K] @ Wt[N,K]^T, fp32 out -------------------
template <int BM>
__global__ __launch_bounds__(256) void gemm_bf_kernel(
    const unsigned short* __restrict__ A, const unsigned short* __restrict__ Wt,
    const float* __restrict__ bias, const float* __restrict__ aux,
    float* __restrict__ C, int M, int Nn, int K, int sig_start) {
  constexpr int TM = BM / 32;  // 4 (BM=128) or 2 (BM=64)
  __shared__ __align__(16) unsigned short As[BM * 32];
  __shared__ __align__(16) unsigned short Bs[128 * 32];
  const int t = threadIdx.x;
  const int wid = t >> 6, lane = t & 63;
  const int quad = lane >> 4, m16 = lane & 15;
  const int wm = (wid >> 1) * (BM / 2), wn = (wid & 1) * 64;
  const int bm = blockIdx.y * BM, bn = blockIdx.x * 128;
  const int swz = quad ^ ((m16 >> 1) & 3);
  const int ci0 = t, ci1 = t + 256;
  const int am0 = ci0 >> 2, ak0 = ((ci0 & 3) ^ ((am0 >> 1) & 3)) * 8;
  const int am1 = ci1 >> 2, ak1 = ((ci1 & 3) ^ ((am1 >> 1) & 3)) * 8;
  const unsigned short* ga0 = A + (size_t)(bm + am0) * K + ak0;
  const unsigned short* ga1 = A + (size_t)(bm + am1) * K + ak1;  // BM==128 only
  const unsigned short* gw0 = Wt + (size_t)(bn + am0) * K + ak0;
  const unsigned short* gw1 = Wt + (size_t)(bn + am1) * K + ak1;
  floatx4 acc[TM][4] = {};
  for (int k0 = 0; k0 < K; k0 += 32) {
    __syncthreads();
#if HAVE_GLL
    ASYNC_COPY16(ga0 + k0, &As[ci0 * 8]);
    if constexpr (BM == 128) ASYNC_COPY16(ga1 + k0, &As[ci1 * 8]);
    ASYNC_COPY16(gw0 + k0, &Bs[ci0 * 8]);
    ASYNC_COPY16(gw1 + k0, &Bs[ci1 * 8]);
#else
    short8 ra0 = *(const short8*)(ga0 + k0);
    short8 rw0 = *(const short8*)(gw0 + k0);
    short8 rw1 = *(const short8*)(gw1 + k0);
    *(short8*)&As[ci0 * 8] = ra0;
    if constexpr (BM == 128) {
      short8 ra1 = *(const short8*)(ga1 + k0);
      *(short8*)&As[ci1 * 8] = ra1;
    }
    *(short8*)&Bs[ci0 * 8] = rw0;
    *(short8*)&Bs[ci1 * 8] = rw1;
#endif
    __syncthreads();
    short8 af[TM], bfv[4];
#pragma unroll
    for (int tm = 0; tm < TM; ++tm)
      af[tm] = *(const short8*)&As[(wm + tm * 16 + m16) * 32 + swz * 8];
#pragma unroll
    for (int tn = 0; tn < 4; ++tn)
      bfv[tn] = *(const short8*)&Bs[(wn + tn * 16 + m16) * 32 + swz * 8];
#pragma unroll
    for (int tm = 0; tm < TM; ++tm)
#pragma unroll
      for (int tn = 0; tn < 4; ++tn)
        acc[tm][tn] = __builtin_amdgcn_mfma_f32_16x16x32_bf16(af[tm], bfv[tn], acc[tm][tn], 0, 0, 0);
  }
#pragma unroll
  for (int tm = 0; tm < TM; ++tm) {
    const int row0 = bm + wm + tm * 16 + quad * 4;
#pragma unroll
    for (int tn = 0; tn < 4; ++tn) {
      const int col = bn + wn + tn * 16 + m16;
      const float badd = bias ? bias[col] : 0.f;
#pragma unroll
      for (int r = 0; r < 4; ++r) {
        float v = acc[tm][tn][r] + badd;
        if (col >= sig_start) v = sigf(v);
        if (aux) v *= aux[(size_t)(row0 + r) * Nn + col];
        C[(size_t)(row0 + r) * Nn + col] = v;
      }
    }
  }
}

// ---------------- pair bias v4: MFMA over h, LN folded, z staged bf16 in LDS --------------
__global__ __launch_bounds__(256, 4) void pairbias3_kernel(
    const float* __restrict__ z, const float* __restrict__ mask,
    const unsigned short* __restrict__ gamWT, const float* __restrict__ pairC,
    unsigned short* __restrict__ pb) {
  __shared__ __align__(16) unsigned short zbf[128 * 136];
  __shared__ float2 pstat[256];
  __shared__ float2 mstat[128];
  const int t = threadIdx.x;
  const int jj = t & 127, half = t >> 7;
  const int b = blockIdx.z, i = blockIdx.y;
  const int j0 = blockIdx.x * 128;
  const float* zrow = &z[((size_t)(b * kN + i) * kN + j0 + jj) * kCP + half * 64];
  float sum = 0.f, ss = 0.f;
#pragma unroll
  for (int g = 0; g < 2; ++g) {
    float4 v[8];
#pragma unroll
    for (int u = 0; u < 8; ++u) v[u] = ((const float4*)zrow)[g * 8 + u];
#pragma unroll
    for (int u = 0; u < 8; ++u) {
      sum += (v[u].x + v[u].y) + (v[u].z + v[u].w);
      ss = fmaf(v[u].x, v[u].x, ss);
      ss = fmaf(v[u].y, v[u].y, ss);
      ss = fmaf(v[u].z, v[u].z, ss);
      ss = fmaf(v[u].w, v[u].w, ss);
    }
#pragma unroll
    for (int k = 0; k < 4; ++k) {
      short8 pk;
      const float4 a = v[2 * k], bb = v[2 * k + 1];
      pk[0] = (short)f2bf(a.x); pk[1] = (short)f2bf(a.y);
      pk[2] = (short)f2bf(a.z); pk[3] = (short)f2bf(a.w);
      pk[4] = (short)f2bf(bb.x); pk[5] = (short)f2bf(bb.y);
      pk[6] = (short)f2bf(bb.z); pk[7] = (short)f2bf(bb.w);
      const int c16 = half * 8 + g * 4 + k;
      *(short8*)&zbf[(jj * 17 + c16) * 8] = pk;
    }
  }
  pstat[t] = make_float2(sum, ss);
  __syncthreads();
  if (t < 128) {
    const float S = pstat[t].x + pstat[t + 128].x;
    const float SS = pstat[t].y + pstat[t + 128].y;
    const float mean = S * (1.f / 128.f);
    const float var = SS * (1.f / 128.f) - mean * mean;
    mstat[t] = make_float2(mean, rsqrtf(var + kEps));
  }
  __syncthreads();
  const int wid = t >> 6, lane = t & 63;
  const int m16 = lane & 15, quad = lane >> 4;
  short8 ga[4];
#pragma unroll
  for (int kk = 0; kk < 4; ++kk)
    ga[kk] = *(const short8*)&gamWT[m16 * 128 + kk * 32 + quad * 8];
  const float4 cb = ((const float4*)pairC)[quad];
  const float4 gs = ((const float4*)pairC)[4 + quad];
#pragma unroll
  for (int u = 0; u < 2; ++u) {
    const int tt = wid * 2 + u;
    const int jloc = tt * 16 + m16;
    floatx4 acc = {};
#pragma unroll
    for (int kk = 0; kk < 4; ++kk) {
      const short8 bf = *(const short8*)&zbf[(jloc * 17 + kk * 4 + quad) * 8];
      acc = __builtin_amdgcn_mfma_f32_16x16x32_bf16(ga[kk], bf, acc, 0, 0, 0);
    }
    const float mean = mstat[jloc].x, rs = mstat[jloc].y;
    const float mk = mask[(size_t)(b * kN + i) * kN + j0 + jloc];
    const size_t obase = ((size_t)(b * kNH + quad * 4) * kN + i) * kN + j0 + jloc;
#pragma unroll
    for (int r = 0; r < 4; ++r) {
      const float gsr = r == 0 ? gs.x : r == 1 ? gs.y : r == 2 ? gs.z : gs.w;
      const float cbr = r == 0 ? cb.x : r == 1 ? cb.y : r == 2 ? cb.z : cb.w;
      const float res = fmaf(rs, fmaf(-mean, gsr, acc[r]), cbr) + mk;
      pb[obase + (size_t)r * kN * kN] = f2bf(res);
    }
  }
}

// ---------------- kvpack: qkvg fp32 -> kbf[bh][j][48] bf16, vtbf[bh][48][j] bf16 ----------
__global__ __launch_bounds__(256) void kvpack_kernel(const float* __restrict__ qkvg,
                                                     unsigned short* __restrict__ kbf,
                                                     unsigned short* __restrict__ vtbf) {
  __shared__ unsigned short vt[48 * 64];
  const int b = blockIdx.z, h = blockIdx.y, j0 = blockIdx.x * 64;
  const int bh = b * kNH + h;
  const int t = threadIdx.x;
  const int j = t >> 2, dq = t & 3;  // d = dq*12 .. +11
  const size_t rowj = (size_t)(b * kN + j0 + j) * (4 * kCT);
  {  // K: straight cast
    const float* src = &qkvg[rowj + kCT + h * kHD + dq * 12];
    float4 v0 = ((const float4*)src)[0];
    float4 v1 = ((const float4*)src)[1];
    float4 v2 = ((const float4*)src)[2];
    uint32_t* dst = (uint32_t*)&kbf[((size_t)bh * kN + j0 + j) * kHD + dq * 12];
    dst[0] = (uint32_t)f2bf(v0.x) | ((uint32_t)f2bf(v0.y) << 16);
    dst[1] = (uint32_t)f2bf(v0.z) | ((uint32_t)f2bf(v0.w) << 16);
    dst[2] = (uint32_t)f2bf(v1.x) | ((uint32_t)f2bf(v1.y) << 16);
    dst[3] = (uint32_t)f2bf(v1.z) | ((uint32_t)f2bf(v1.w) << 16);
    dst[4] = (uint32_t)f2bf(v2.x) | ((uint32_t)f2bf(v2.y) << 16);
    dst[5] = (uint32_t)f2bf(v2.z) | ((uint32_t)f2bf(v2.w) << 16);
  }
  {  // V -> LDS transposed
    const float* src = &qkvg[rowj + 2 * kCT + h * kHD + dq * 12];
    float4 v0 = ((const float4*)src)[0];
    float4 v1 = ((const float4*)src)[1];
    float4 v2 = ((const float4*)src)[2];
    float vv[12] = {v0.x, v0.y, v0.z, v0.w, v1.x, v1.y, v1.z, v1.w,
                    v2.x, v2.y, v2.z, v2.w};
#pragma unroll
    for (int e = 0; e < 12; ++e) vt[(dq * 12 + e) * 64 + j] = f2bf(vv[e]);
  }
  __syncthreads();
#pragma unroll
  for (int r = 0; r < 2; ++r) {
    int ch = t + r * 256;
    if (ch < 384) {
      int d = ch >> 3, jo = (ch & 7) * 8;
      short8 v = *(const short8*)&vt[d * 64 + jo];
      *(short8*)&vtbf[((size_t)bh * kHD + d) * kN + j0 + jo] = v;
    }
  }
}

// ---------------- attn2: MFMA flash attention, swapped QK^T, 4 waves x 16 i ---------------
// Block = (b,h, 64 i-rows). Per 64-j chunk: S^T=mfma(K,Q) (lane: i=m16, 16 j's),
// in-register online softmax, P->bf16 via cvt_pk + ds_bpermute redistribution,
// O^T=mfma(V^T,P^T). K/V double-buffered in LDS via global_load_lds prefetch.
// V^T tile XOR-swizzled (pre-swizzled global src + swizzled read; rule #21).
__global__ __launch_bounds__(256, 4) void attn2_kernel(
    const float* __restrict__ qkvg, const unsigned short* __restrict__ kbf,
    const unsigned short* __restrict__ vtbf, const unsigned short* __restrict__ pb,
    unsigned short* __restrict__ o_out) {
  __shared__ __align__(16) unsigned short lds[4 * 3072];  // [kbA][vtA][kbB][vtB]
  const int b = blockIdx.z, h = blockIdx.y, bh = b * kNH + h;
  const int t = threadIdx.x, wid = t >> 6, lane = t & 63;
  const int m16 = lane & 15, quad = lane >> 4;
  const int i = blockIdx.x * 64 + wid * 16 + m16;
  // Q fragments (B-operand): element e of qf[ks] = Q[i][ks*32+quad*8+e] * scale
  short8 qf[2];
  {
    const float* qrow = &qkvg[(size_t)(b * kN + i) * (4 * kCT) + h * kHD];
    float4 a = *(const float4*)(qrow + quad * 8);
    float4 bb = *(const float4*)(qrow + quad * 8 + 4);
    float v0[8] = {a.x, a.y, a.z, a.w, bb.x, bb.y, bb.z, bb.w};
#pragma unroll
    for (int e = 0; e < 8; ++e) qf[0][e] = (short)f2bf(v0[e] * kQScale);
    short8 z8 = {};
    qf[1] = z8;
    if (quad < 2) {
      float4 c = *(const float4*)(qrow + 32 + quad * 8);
      float4 d = *(const float4*)(qrow + 32 + quad * 8 + 4);
      float v1[8] = {c.x, c.y, c.z, c.w, d.x, d.y, d.z, d.w};
#pragma unroll
      for (int e = 0; e < 8; ++e) qf[1][e] = (short)f2bf(v1[e] * kQScale);
    }
  }
  // staging: 12 slabs of 1024B per chunk (6 kb + 6 vt), 3 per wave.
  // vt slabs: LDS write linear, global source column pre-swizzled by row&7.
  auto stage = [&](int sel, int c) {
#pragma unroll
    for (int l = wid; l < 12; l += 4) {
      if (l < 6) {
        const unsigned short* src = kbf + (size_t)bh * (kN * kHD) + c * 3072 + l * 512 + lane * 8;
#if HAVE_GLL
        ASYNC_COPY16(src, &lds[sel * 6144 + l * 512 + lane * 8]);
#else
        short8 tmp = *(const short8*)src;
        *(short8*)&lds[sel * 6144 + l * 512 + lane * 8] = tmp;
#endif
      } else {
        const int k = l - 6;
        const int row = 8 * k + (lane >> 3);
        const int colsw = ((lane & 7) ^ (lane >> 3)) * 8;  // inverse-swizzled source
        const unsigned short* src = vtbf + ((size_t)bh * kHD + row) * kN + c * 64 + colsw;
#if HAVE_GLL
        ASYNC_COPY16(src, &lds[sel * 6144 + 3072 + k * 512 + lane * 8]);
#else
        short8 tmp = *(const short8*)src;
        *(short8*)&lds[sel * 6144 + 3072 + k * 512 + lane * 8] = tmp;
#endif
      }
    }
  };
  floatx4 oacc[3] = {};
  float mrun = -INFINITY, lsum = 0.f;
  const unsigned short* pbrow = &pb[((size_t)bh * kN + i) * kN];
  const int addrA = (m16 + ((quad & 1) ? 32 : 0)) * 4;  // bpermute byte addr
  const int addrB = addrA + 64;
  stage(0, 0);
  for (int c = 0; c < 12; ++c) {
    __syncthreads();  // drains vmcnt -> buf[c&1] ready; buf[(c+1)&1] free
    if (c < 11) stage((c + 1) & 1, c + 1);
    const unsigned short* kb = &lds[(c & 1) * 6144];
    const unsigned short* vt = kb + 3072;
    // QK^T: lane holds S[j = c*64 + jt*16 + quad*4 + r][i = m16] (+ pair bias)
    float s[4][4];
#pragma unroll
    for (int jt = 0; jt < 4; ++jt) {
      short8 kf0 = *(const short8*)&kb[(jt * 16 + m16) * 48 + quad * 8];
      short8 kf1 = *(const short8*)&kb[(jt * 16 + m16) * 48 + 32 + quad * 8];
      floatx4 acc = {};
      acc = __builtin_amdgcn_mfma_f32_16x16x32_bf16(kf0, qf[0], acc, 0, 0, 0);
      acc = __builtin_amdgcn_mfma_f32_16x16x32_bf16(kf1, qf[1], acc, 0, 0, 0);
      ushort4 pbv = *(const ushort4*)&pbrow[c * 64 + jt * 16 + quad * 4];
      s[jt][0] = acc[0] + bf2f(pbv.x);
      s[jt][1] = acc[1] + bf2f(pbv.y);
      s[jt][2] = acc[2] + bf2f(pbv.z);
      s[jt][3] = acc[3] + bf2f(pbv.w);
    }
    // online softmax (per i = m16; stats replicated across quads)
    float smax = s[0][0];
#pragma unroll
    for (int jt = 0; jt < 4; ++jt)
#pragma unroll
      for (int r = 0; r < 4; ++r) smax = fmaxf(smax, s[jt][r]);
    float cm = fmaxf(smax, __shfl_xor(smax, 16));
    cm = fmaxf(cm, __shfl_xor(cm, 32));
    const float mnew = fmaxf(mrun, cm);
    const float alpha = expf(mrun - mnew);
    float p[4][4];
    float psum = 0.f;
#pragma unroll
    for (int jt = 0; jt < 4; ++jt)
#pragma unroll
      for (int r = 0; r < 4; ++r) {
        p[jt][r] = expf(s[jt][r] - mnew);
        psum += p[jt][r];
      }
    psum += __shfl_xor(psum, 16);
    psum += __shfl_xor(psum, 32);
    lsum = fmaf(lsum, alpha, psum);
    mrun = mnew;
    // pack P to bf16 pairs: pk[t][rp] = (p[t][2rp], p[t][2rp+1])
    uint32_t pk[4][2];
#pragma unroll
    for (int jt = 0; jt < 4; ++jt) {
      pk[jt][0] = cvtpk(p[jt][0], p[jt][1]);
      pk[jt][1] = cvtpk(p[jt][2], p[jt][3]);
    }
    // rescale O
#pragma unroll
    for (int dt = 0; dt < 3; ++dt)
#pragma unroll
      for (int r = 0; r < 4; ++r) oacc[dt][r] *= alpha;
    // PV: B-frag element e = P[i=m16][j = kp*32 + quad*8 + e]
#pragma unroll
    for (int kp = 0; kp < 2; ++kp) {
      const int tA = 2 * kp, tB = 2 * kp + 1;
      uint32_t xA0 = (uint32_t)__builtin_amdgcn_ds_bpermute(addrA, (int)pk[tA][0]);
      uint32_t xA1 = (uint32_t)__builtin_amdgcn_ds_bpermute(addrA, (int)pk[tA][1]);
      uint32_t yA0 = (uint32_t)__builtin_amdgcn_ds_bpermute(addrA, (int)pk[tB][0]);
      uint32_t yA1 = (uint32_t)__builtin_amdgcn_ds_bpermute(addrA, (int)pk[tB][1]);
      uint32_t xB0 = (uint32_t)__builtin_amdgcn_ds_bpermute(addrB, (int)pk[tA][0]);
      uint32_t xB1 = (uint32_t)__builtin_amdgcn_ds_bpermute(addrB, (int)pk[tA][1]);
      uint32_t yB0 = (uint32_t)__builtin_amdgcn_ds_bpermute(addrB, (int)pk[tB][0]);
      uint32_t yB1 = (uint32_t)__builtin_amdgcn_ds_bpermute(addrB, (int)pk[tB][1]);
      const bool hi = quad >= 2;  // t' = quad>>1 + 2kp
      intx4 pi;
      pi[0] = (int)(hi ? yA0 : xA0);
      pi[1] = (int)(hi ? yA1 : xA1);
      pi[2] = (int)(hi ? yB0 : xB0);
      pi[3] = (int)(hi ? yB1 : xB1);
      const short8 pf = __builtin_bit_cast(short8, pi);
#pragma unroll
      for (int dt = 0; dt < 3; ++dt) {
        const int colsw = ((kp * 4 + quad) ^ (m16 & 7)) * 8;  // swizzled read
        short8 vf = *(const short8*)&vt[(dt * 16 + m16) * 64 + colsw];
        oacc[dt] = __builtin_amdgcn_mfma_f32_16x16x32_bf16(vf, pf, oacc[dt], 0, 0, 0);
      }
    }
  }
  // epilogue: lane holds O[i=m16][d = dt*16 + quad*4 + r]
  const float inv = 1.f / lsum;
  const float* grow = &qkvg[(size_t)(b * kN + i) * (4 * kCT) + 3 * kCT + h * kHD];
  unsigned short* orow = &o_out[(size_t)(b * kN + i) * kCT + h * kHD];
#pragma unroll
  for (int dt = 0; dt < 3; ++dt) {
    float4 g4 = *(const float4*)&grow[dt * 16 + quad * 4];
    const float o0 = oacc[dt][0] * inv * g4.x;
    const float o1 = oacc[dt][1] * inv * g4.y;
    const float o2 = oacc[dt][2] * inv * g4.z;
    const float o3 = oacc[dt][3] * inv * g4.w;
    uint32_t u0 = (uint32_t)f2bf(o0) | ((uint32_t)f2bf(o1) << 16);
    uint32_t u1 = (uint32_t)f2bf(o2) | ((uint32_t)f2bf(o3) << 16);
    *(uint32_t*)&orow[dt * 16 + quad * 4 + 0] = u0;
    *(uint32_t*)&orow[dt * 16 + quad * 4 + 2] = u1;
  }
}

// ==========================================================================================
extern "C" void kernel_launch(void* const* d_in, const int* in_sizes, int n_in,
                              void* d_out, int out_size, void* d_ws, size_t ws_size,
                              hipStream_t stream) {
  const float* a      = (const float*)d_in[0];
  const float* s      = (const float*)d_in[1];
  const float* z      = (const float*)d_in[2];
  const float* mask   = (const float*)d_in[3];
  const float* Wg_ada = (const float*)d_in[4];
  const float* bg_ada = (const float*)d_in[5];
  const float* Wb_ada = (const float*)d_in[6];
  const float* Wq     = (const float*)d_in[7];
  const float* bq     = (const float*)d_in[8];
  const float* Wk     = (const float*)d_in[9];
  const float* Wv     = (const float*)d_in[10];
  const float* Wpb    = (const float*)d_in[11];
  const float* pn_g   = (const float*)d_in[12];
  const float* pn_b   = (const float*)d_in[13];
  const float* Wgate  = (const float*)d_in[14];
  const float* Wout   = (const float*)d_in[15];
  const float* Wog    = (const float*)d_in[16];
  const float* bog    = (const float*)d_in[17];
  float* out = (float*)d_out;

  char* p = (char*)d_ws;
  auto alloc = [&](size_t bytes) -> char* {
    char* r = p;
    p += (bytes + 255) & ~(size_t)255;
    return r;
  };
  float* a_ln  = (float*)alloc((size_t)1536 * 768 * 4);
  float* gb    = (float*)alloc((size_t)1536 * 1536 * 4);
  float* qkvg  = (float*)alloc((size_t)1536 * 3072 * 4);
  float* ogate = (float*)alloc((size_t)1536 * 768 * 4);
  unsigned short* s_ln   = (unsigned short*)alloc((size_t)1536 * 384 * 2);
  unsigned short* a_nrm  = (unsigned short*)alloc((size_t)1536 * 768 * 2);
  unsigned short* s_bf   = (unsigned short*)alloc((size_t)1536 * 384 * 2);
  unsigned short* o_g    = (unsigned short*)alloc((size_t)1536 * 768 * 2);
  unsigned short* pbias  = (unsigned short*)alloc((size_t)2 * 16 * 768 * 768 * 2);
  unsigned short* p_adaT = (unsigned short*)alloc((size_t)1536 * 384 * 2);
  unsigned short* p_qkvT = (unsigned short*)alloc((size_t)3072 * 768 * 2);
  unsigned short* WogT   = (unsigned short*)alloc((size_t)768 * 384 * 2);
  unsigned short* WoutT  = (unsigned short*)alloc((size_t)768 * 768 * 2);
  unsigned short* kbf    = (unsigned short*)alloc((size_t)32 * 768 * 48 * 2);
  unsigned short* vtbf   = (unsigned short*)alloc((size_t)32 * 48 * 768 * 2);
  unsigned short* gamWT  = (unsigned short*)alloc(2048 * 2);
  float* pb_ada = (float*)alloc(1536 * 4);
  float* pb_qk  = (float*)alloc(3072 * 4);
  float* pairC  = (float*)alloc(32 * 4);

  transpose_pack_kernel<<<dim3(3744), 256, 0, stream>>>(
      Wg_ada, Wb_ada, Wq, Wk, Wv, Wgate, Wog, Wout, p_adaT, p_qkvT, WogT, WoutT);
  const int packTot = 1536 + 3072 + 1536 * 384 + 2048 + 32;
  pack_kernel<<<dim3((packTot + 255) / 256), 256, 0, stream>>>(
      bg_ada, bq, s, Wpb, pn_g, pn_b, pb_ada, pb_qk, s_bf, gamWT, pairC);
  ln_kernel<768><<<dim3(1536), 256, 0, stream>>>(a, a_ln);
  ln_bf_kernel<384><<<dim3(1536), 256, 0, stream>>>(s, s_ln);
  gemm_bf_kernel<64><<<dim3(12, 24), 256, 0, stream>>>(
      s_ln, p_adaT, pb_ada, nullptr, gb, 1536, 1536, 384, 1 << 30);
  anorm_kernel<<<dim3(1536 * 768 / 256), 256, 0, stream>>>(gb, a_ln, a_nrm);
  gemm_bf_kernel<128><<<dim3(24, 12), 256, 0, stream>>>(
      a_nrm, p_qkvT, pb_qk, nullptr, qkvg, 1536, 3072, 768, 2304);
  gemm_bf_kernel<64><<<dim3(6, 24), 256, 0, stream>>>(
      s_bf, WogT, bog, nullptr, ogate, 1536, 768, 384, 0);
  pairbias3_kernel<<<dim3(6, 768, 2), 256, 0, stream>>>(z, mask, gamWT, pairC, pbias);
  kvpack_kernel<<<dim3(12, 16, 2), 256, 0, stream>>>(qkvg, kbf, vtbf);
  attn2_kernel<<<dim3(12, 16, 2), 256, 0, stream>>>(qkvg, kbf, vtbf, pbias, o_g);
  gemm_bf_kernel<64><<<dim3(6, 24), 256, 0, stream>>>(
      o_g, WoutT, nullptr, ogate, out, 1536, 768, 768, 1 << 30);
}